// Round 1
// 278.614 us; speedup vs baseline: 1.0568x; 1.0568x over previous
//
#include <hip/hip_runtime.h>

// Problem constants (LoRAExpert)
#define T_TOK 16384
#define NEXP 8
#define DIN 1024
#define DOUT 1024
#define NADP 8
#define RANK 16
#define NGRP 64        // E*A groups (convert kernel)
#define MAXTILES 135   // base gemm: 128 full + up to 7 remainders (128-row tiles)
#define MAXP1 264      // pass1: 256 full + up to 8 remainders (64-row tiles)
#define BK 64          // base gemm K-tile

typedef float f32x4 __attribute__((ext_vector_type(4)));
typedef __bf16 bf16x8 __attribute__((ext_vector_type(8)));

typedef __attribute__((address_space(3))) void lds_void;
typedef __attribute__((address_space(1))) void g_void;

static __device__ __forceinline__ unsigned short f2bf(float f) {
    union { float f; unsigned u; } c; c.f = f;
    unsigned r = c.u + 0x7FFFu + ((c.u >> 16) & 1u);
    return (unsigned short)(r >> 16);
}

// ================= fused converts =================
// [0,NBX): x->bf16 ; [NBX,NBX+NBW): W->Wt ; then NGRP blocks lora_A->Agt ; then 64 blocks lB->Blt
#define NBX 16512
#define NBW 2048
__global__ __launch_bounds__(256) void k_convert_all(const float* __restrict__ x,
                                                     const float* __restrict__ W,
                                                     const float* __restrict__ lA,
                                                     const float* __restrict__ lB,
                                                     unsigned short* __restrict__ xb,
                                                     unsigned short* __restrict__ Wt,
                                                     unsigned short* __restrict__ Agt,
                                                     unsigned short* __restrict__ Blt) {
    __shared__ __attribute__((aligned(16))) unsigned short lds_u[16 * 1032]; // 33 KB union
    int b = blockIdx.x;
    int t = threadIdx.x;
    if (b < NBX) {
        // ---- convert x, zero-pad 128 extra rows ----
        size_t i = ((size_t)b * 256 + t) * 4;
        ushort4 u;
        if (i < (size_t)T_TOK * DIN) {
            float4 v = *(const float4*)(x + i);
            u.x = f2bf(v.x); u.y = f2bf(v.y); u.z = f2bf(v.z); u.w = f2bf(v.w);
        } else {
            u.x = 0; u.y = 0; u.z = 0; u.w = 0;
        }
        *(ushort4*)(xb + i) = u;
    } else if (b < NBX + NBW) {
        // ---- convert+transpose W [E][IN][OUT] -> [E][OUT][IN] ----
        int idx = b - NBX;
        int e = idx >> 8;
        int k0 = ((idx >> 4) & 15) * 64, n0 = (idx & 15) * 64;
        const float* We = W + (size_t)e * DIN * DOUT;
        unsigned short* Wte = Wt + (size_t)e * DIN * DOUT;
        int kr = t >> 2;
        int nc = (t & 3) * 16;
#pragma unroll
        for (int j = 0; j < 4; j++) {
            float4 v = *(const float4*)(We + (size_t)(k0 + kr) * DOUT + n0 + nc + j * 4);
            lds_u[(nc + j * 4 + 0) * 80 + kr] = f2bf(v.x);
            lds_u[(nc + j * 4 + 1) * 80 + kr] = f2bf(v.y);
            lds_u[(nc + j * 4 + 2) * 80 + kr] = f2bf(v.z);
            lds_u[(nc + j * 4 + 3) * 80 + kr] = f2bf(v.w);
        }
        __syncthreads();
        int n = t >> 2;
        int kk = (t & 3) * 16;
        uint4 v0 = *(const uint4*)&lds_u[n * 80 + kk];
        uint4 v1 = *(const uint4*)&lds_u[n * 80 + kk + 8];
        *(uint4*)(Wte + (size_t)(n0 + n) * DIN + k0 + kk) = v0;
        *(uint4*)(Wte + (size_t)(n0 + n) * DIN + k0 + kk + 8) = v1;
    } else if (b < NBX + NBW + NGRP) {
        // ---- convert+transpose lora_A [A][E][K][R] -> Agt [g=e*8+a][R][K] ----
        int g = b - (NBX + NBW);
        int a = g & 7, e = g >> 3;
        const float* src = lA + (size_t)(a * NEXP + e) * DIN * RANK;
#pragma unroll
        for (int it = 0; it < 4; it++) {
            int k = it * 256 + t;
            const float4* p = (const float4*)(src + (size_t)k * RANK);
            float4 v0 = p[0], v1 = p[1], v2 = p[2], v3 = p[3];
            lds_u[0 * 1032 + k] = f2bf(v0.x);  lds_u[1 * 1032 + k] = f2bf(v0.y);
            lds_u[2 * 1032 + k] = f2bf(v0.z);  lds_u[3 * 1032 + k] = f2bf(v0.w);
            lds_u[4 * 1032 + k] = f2bf(v1.x);  lds_u[5 * 1032 + k] = f2bf(v1.y);
            lds_u[6 * 1032 + k] = f2bf(v1.z);  lds_u[7 * 1032 + k] = f2bf(v1.w);
            lds_u[8 * 1032 + k] = f2bf(v2.x);  lds_u[9 * 1032 + k] = f2bf(v2.y);
            lds_u[10 * 1032 + k] = f2bf(v2.z); lds_u[11 * 1032 + k] = f2bf(v2.w);
            lds_u[12 * 1032 + k] = f2bf(v3.x); lds_u[13 * 1032 + k] = f2bf(v3.y);
            lds_u[14 * 1032 + k] = f2bf(v3.z); lds_u[15 * 1032 + k] = f2bf(v3.w);
        }
        __syncthreads();
        unsigned short* dst = Agt + (size_t)g * RANK * DIN;
        int r = t >> 4, ks = (t & 15) * 64;
#pragma unroll
        for (int j = 0; j < 8; j++)
            *(uint4*)(dst + r * DIN + ks + j * 8) = *(const uint4*)&lds_u[r * 1032 + ks + j * 8];
    } else {
        // ---- lB [A][E][R][N] fp32 -> Blt [E][N][A*16+R] bf16 (B^T operand for lora MFMA) ----
        int idx = b - (NBX + NBW + NGRP);
        int e = idx >> 3, nc = idx & 7;           // n chunk of 128
        int k = t >> 1, half = t & 1;
        int a = k >> 4, r = k & 15;
        const float* src = lB + ((size_t)(a * NEXP + e) * RANK + r) * DOUT + nc * 128 + half * 64;
#pragma unroll
        for (int j = 0; j < 16; j++) {
            float4 v = *(const float4*)(src + j * 4);
            int nl = half * 64 + j * 4;
            lds_u[k * 129 + nl + 0] = f2bf(v.x);
            lds_u[k * 129 + nl + 1] = f2bf(v.y);
            lds_u[k * 129 + nl + 2] = f2bf(v.z);
            lds_u[k * 129 + nl + 3] = f2bf(v.w);
        }
        __syncthreads();
        int nl = t >> 1, kh = t & 1;
        unsigned short* dst = Blt + ((size_t)(e * 1024 + nc * 128 + nl)) * 128 + kh * 64;
#pragma unroll
        for (int g2 = 0; g2 < 8; g2++) {
            uint4 pv;
            unsigned short s0 = lds_u[(kh * 64 + g2 * 8 + 0) * 129 + nl];
            unsigned short s1 = lds_u[(kh * 64 + g2 * 8 + 1) * 129 + nl];
            unsigned short s2 = lds_u[(kh * 64 + g2 * 8 + 2) * 129 + nl];
            unsigned short s3 = lds_u[(kh * 64 + g2 * 8 + 3) * 129 + nl];
            unsigned short s4 = lds_u[(kh * 64 + g2 * 8 + 4) * 129 + nl];
            unsigned short s5 = lds_u[(kh * 64 + g2 * 8 + 5) * 129 + nl];
            unsigned short s6 = lds_u[(kh * 64 + g2 * 8 + 6) * 129 + nl];
            unsigned short s7 = lds_u[(kh * 64 + g2 * 8 + 7) * 129 + nl];
            pv.x = (unsigned)s0 | ((unsigned)s1 << 16);
            pv.y = (unsigned)s2 | ((unsigned)s3 << 16);
            pv.z = (unsigned)s4 | ((unsigned)s5 << 16);
            pv.w = (unsigned)s6 | ((unsigned)s7 << 16);
            *(uint4*)(dst + g2 * 8) = pv;
        }
    }
}

// ================= pass1: inter[tok] = s_a * (x[tok] @ lora_A[e, a(tok)]) as bf16 =========
// No routing, no LDS, no barriers. 64-row tiles of one expert, inline schedule from gs.
// Each wave owns 2 adapters and all 4 rowgroups; computes all 8 adapters per token and
// stores only the token's own adapter (masked), pre-scaled, as bf16.
__global__ __launch_bounds__(256) void k_pass1(const unsigned short* __restrict__ xb,
                                               const unsigned short* __restrict__ Agt,
                                               const int* __restrict__ gs,
                                               const int* __restrict__ aidx,
                                               const float* __restrict__ scal,
                                               unsigned short* __restrict__ interb) {
    int bid = blockIdx.x;
    int e = -1, m0 = 0, valid = 0;
    {
        int acc_t = 0, base = 0;
#pragma unroll
        for (int ee = 0; ee < NEXP; ee++) {
            int sz = gs[ee];
            int nt = (sz + 63) >> 6;
            if (e < 0 && bid < acc_t + nt) {
                int loc = bid - acc_t;
                e = ee; m0 = base + (loc << 6);
                int v = sz - (loc << 6); valid = v > 64 ? 64 : v;
            }
            acc_t += nt; base += sz;
        }
    }
    if (e < 0) return;

    int t = threadIdx.x;
    int lane = t & 63, w = t >> 6;   // wave owns adapters 2w, 2w+1
    int ln = lane & 15, q = lane >> 4;

    const unsigned short* A0 = Agt + ((size_t)(e * NADP + 2 * w) * RANK + ln) * DIN + q * 8;
    const unsigned short* A1 = A0 + (size_t)RANK * DIN;
    const unsigned short* X0 = xb + (size_t)(m0 + ln) * DIN + q * 8;

    f32x4 acc[4][2];
#pragma unroll
    for (int i = 0; i < 4; i++) {
        acc[i][0] = (f32x4){0.f, 0.f, 0.f, 0.f};
        acc[i][1] = (f32x4){0.f, 0.f, 0.f, 0.f};
    }

    // swapped operands: D[row = rank r][col = token], lane holds one token column,
    // regs = 4 consecutive r at q*4.
#pragma unroll 2
    for (int k0 = 0; k0 < DIN; k0 += 32) {
        bf16x8 b0 = *(const bf16x8*)(A0 + k0);
        bf16x8 b1 = *(const bf16x8*)(A1 + k0);
#pragma unroll
        for (int rg = 0; rg < 4; rg++) {
            bf16x8 af = *(const bf16x8*)(X0 + (size_t)(rg * 16) * DIN + k0);
            acc[rg][0] = __builtin_amdgcn_mfma_f32_16x16x32_bf16(b0, af, acc[rg][0], 0, 0, 0);
            acc[rg][1] = __builtin_amdgcn_mfma_f32_16x16x32_bf16(b1, af, acc[rg][1], 0, 0, 0);
        }
    }

    float s0 = scal[2 * w], s1 = scal[2 * w + 1];
#pragma unroll
    for (int rg = 0; rg < 4; rg++) {
        int tr = rg * 16 + ln;
        if (tr < valid) {
            int tok = m0 + tr;
            int a = aidx[tok];
            if (a == 2 * w) {
                f32x4 v = acc[rg][0];
                ushort4 u;
                u.x = f2bf(s0 * v[0]); u.y = f2bf(s0 * v[1]);
                u.z = f2bf(s0 * v[2]); u.w = f2bf(s0 * v[3]);
                *(ushort4*)(interb + (size_t)tok * RANK + q * 4) = u;
            } else if (a == 2 * w + 1) {
                f32x4 v = acc[rg][1];
                ushort4 u;
                u.x = f2bf(s1 * v[0]); u.y = f2bf(s1 * v[1]);
                u.z = f2bf(s1 * v[2]); u.w = f2bf(s1 * v[3]);
                *(ushort4*)(interb + (size_t)tok * RANK + q * 4) = u;
            }
        }
    }
}

// ================= base grouped GEMM + fused LoRA-B, bf16 MFMA, 128x128xBK ===============
// grid = dim3(8, MAXTILES). Double-buffered LDS: stage(k+1) overlaps compute(k),
// ONE __syncthreads per K-step (T3 minimum 2-phase). Inline schedule from gs.
__global__ __launch_bounds__(256) void k_gemm(const unsigned short* __restrict__ xb,
                                              const unsigned short* __restrict__ wt,
                                              const int* __restrict__ gs,
                                              const unsigned short* __restrict__ interb,
                                              const int* __restrict__ aidx,
                                              const unsigned short* __restrict__ Blt,
                                              float* __restrict__ out) {
    __shared__ __attribute__((aligned(16))) unsigned short smem[32768]; // 64 KB = 2 x (As 16K + Bs 16K)
    int tileid = blockIdx.y;
    int e = -1, m0 = 0, valid = 0;
    {
        int acc_t = 0, base = 0;
#pragma unroll
        for (int ee = 0; ee < NEXP; ee++) {
            int sz = gs[ee];
            int nt = (sz + 127) >> 7;
            if (e < 0 && tileid < acc_t + nt) {
                int loc = tileid - acc_t;
                e = ee; m0 = base + (loc << 7);
                int v = sz - (loc << 7); valid = v > 128 ? 128 : v;
            }
            acc_t += nt; base += sz;
        }
    }
    if (e < 0) return;
    int n0 = blockIdx.x * 128;

    int t = threadIdx.x;
    int lane = t & 63;
    int wave = t >> 6;
    int wm = wave >> 1, wn = wave & 1;
    int ln = lane & 15, q = lane >> 4;

    const unsigned short* wte = wt + (size_t)e * DIN * DOUT;

    f32x4 acc[4][4];
#pragma unroll
    for (int i = 0; i < 4; i++)
#pragma unroll
        for (int j = 0; j < 4; j++) acc[i][j] = (f32x4){0.f, 0.f, 0.f, 0.f};

    // staging: lane loads global chunk g = (lane&7)^(row&7) so physical LDS slot lane&7
    // holds swizzled content; LDS dest = wave-uniform base + lane*16 (HW constraint).
    int srow[4], skoff[4];
#pragma unroll
    for (int j = 0; j < 4; j++) {
        srow[j]  = j * 32 + wave * 8 + (lane >> 3);
        skoff[j] = ((lane & 7) ^ (srow[j] & 7)) * 8;
    }

    auto STAGE = [&](int buf, int k0) {
#pragma unroll
        for (int j = 0; j < 4; j++) {
            __builtin_amdgcn_global_load_lds(
                (const g_void*)(xb + (size_t)(m0 + srow[j]) * DIN + k0 + skoff[j]),
                (lds_void*)((char*)smem + buf * 32768 + j * 4096 + wave * 1024), 16, 0, 0);
            __builtin_amdgcn_global_load_lds(
                (const g_void*)(wte + (size_t)(n0 + srow[j]) * DIN + k0 + skoff[j]),
                (lds_void*)((char*)smem + buf * 32768 + 16384 + j * 4096 + wave * 1024), 16, 0, 0);
        }
    };

    auto COMPUTE = [&](int buf) {
        const char* Ab = (const char*)smem + buf * 32768;
        const char* Bb = Ab + 16384;
#pragma unroll
        for (int kf = 0; kf < 2; kf++) {
            bf16x8 af[4], bfr[4];
#pragma unroll
            for (int mi = 0; mi < 4; mi++) {
                int row = wm * 64 + mi * 16 + ln;
                int slot = (kf * 4 + q) ^ (ln & 7);      // row&7 == ln&7
                af[mi] = *(const bf16x8*)(Ab + row * 128 + slot * 16);
            }
#pragma unroll
            for (int ni = 0; ni < 4; ni++) {
                int row = wn * 64 + ni * 16 + ln;
                int slot = (kf * 4 + q) ^ (ln & 7);
                bfr[ni] = *(const bf16x8*)(Bb + row * 128 + slot * 16);
            }
#pragma unroll
            for (int mi = 0; mi < 4; mi++)
#pragma unroll
                for (int ni = 0; ni < 4; ni++)
                    acc[mi][ni] = __builtin_amdgcn_mfma_f32_16x16x32_bf16(af[mi], bfr[ni], acc[mi][ni], 0, 0, 0);
        }
    };

    // prologue: fill buffer 0
    STAGE(0, 0);
    __syncthreads();
    int cur = 0;
    for (int k0 = BK; k0 < DIN; k0 += BK) {
        STAGE(cur ^ 1, k0);   // prefetch next tile — latency hides under COMPUTE
        COMPUTE(cur);
        __syncthreads();      // drains vmcnt (prefetch done by now) + lgkm, flips buffer
        cur ^= 1;
    }
    COMPUTE(cur);

    // ---- fused LoRA: acc += P @ Blt[e][n0 slab], P[row][a*16+r] = interb[row][r] at slot a ----
    __syncthreads();
    {
        // fold zeroing into the scatter: 2 threads/row each cover 8 of 16 logical slots
        int row = t >> 1, h = t & 1;
        int rs = row & 15;
        uint4 z = {0u, 0u, 0u, 0u};
        uint4 payload = z;
        int pslot = -1;
        if (row < valid) {
            int tok = m0 + row;
            int a = aidx[tok];
            payload = *(const uint4*)(interb + (size_t)tok * RANK + h * 8); // pre-scaled bf16
            pslot = a * 2 + h;
        }
#pragma unroll
        for (int l2 = 0; l2 < 8; l2++) {
            int l = l2 * 2 + h;                       // logical slot, parity h
            int phys = l ^ rs;                        // 16-slot xor swizzle
            *(uint4*)((char*)smem + row * 256 + phys * 16) = (l == pslot) ? payload : z;
        }
    }
    __syncthreads();
#pragma unroll
    for (int kf = 0; kf < 4; kf++) {
        bf16x8 af[4], bfr[4];
        const unsigned short* bbase = Blt + ((size_t)(e * 1024 + n0 + wn * 64 + ln)) * 128 + kf * 32 + q * 8;
#pragma unroll
        for (int ni = 0; ni < 4; ni++)
            bfr[ni] = *(const bf16x8*)(bbase + (size_t)ni * 16 * 128);
#pragma unroll
        for (int mi = 0; mi < 4; mi++) {
            int row = wm * 64 + mi * 16 + ln;
            int slot = (kf * 4 + q) ^ ln;             // row&15 == ln
            af[mi] = *(const bf16x8*)((const char*)smem + row * 256 + slot * 16);
        }
#pragma unroll
        for (int mi = 0; mi < 4; mi++)
#pragma unroll
            for (int ni = 0; ni < 4; ni++)
                acc[mi][ni] = __builtin_amdgcn_mfma_f32_16x16x32_bf16(af[mi], bfr[ni], acc[mi][ni], 0, 0, 0);
    }

    // ---- store (single writer of out) ----
#pragma unroll
    for (int mi = 0; mi < 4; mi++) {
#pragma unroll
        for (int r = 0; r < 4; r++) {
            int row_l = wm * 64 + mi * 16 + q * 4 + r;
            if (row_l < valid) {
                float* orow = out + (size_t)(m0 + row_l) * DOUT + n0 + wn * 64 + ln;
#pragma unroll
                for (int ni = 0; ni < 4; ni++)
                    orow[ni * 16] = acc[mi][ni][r];
            }
        }
    }
}

extern "C" void kernel_launch(void* const* d_in, const int* in_sizes, int n_in,
                              void* d_out, int out_size, void* d_ws, size_t ws_size,
                              hipStream_t stream) {
    (void)in_sizes; (void)n_in; (void)out_size; (void)ws_size;
    const float* x    = (const float*)d_in[0];
    const int*   gs   = (const int*)d_in[1];
    const int*   aidx = (const int*)d_in[2];
    const float* W    = (const float*)d_in[3];
    const float* lA   = (const float*)d_in[4];
    const float* lB   = (const float*)d_in[5];
    const float* scal = (const float*)d_in[6];
    float* out = (float*)d_out;

    // ws layout (16B-aligned)
    char* ws = (char*)d_ws;
    unsigned short* xb     = (unsigned short*)ws;        size_t o = 33816576; // (T+128)*1024*2
    unsigned short* wt     = (unsigned short*)(ws + o);  o += 16777216;       // E*IN*OUT*2
    unsigned short* Agt    = (unsigned short*)(ws + o);  o += 2097152;        // 64*16*1024*2
    unsigned short* Blt    = (unsigned short*)(ws + o);  o += 2097152;        // 8*1024*128*2
    unsigned short* interb = (unsigned short*)(ws + o);  o += 524288;         // T*16*2 (bf16, pre-scaled)

    k_convert_all<<<NBX + NBW + NGRP + 64, 256, 0, stream>>>(x, W, lA, lB, xb, wt, Agt, Blt);
    k_pass1<<<MAXP1, 256, 0, stream>>>(xb, Agt, gs, aidx, scal, interb);
    k_gemm<<<dim3(8, MAXTILES), 256, 0, stream>>>(xb, wt, gs, interb, aidx, Blt, out);
}

// Round 2
// 276.337 us; speedup vs baseline: 1.0655x; 1.0082x over previous
//
#include <hip/hip_runtime.h>

// Problem constants (LoRAExpert)
#define T_TOK 16384
#define NEXP 8
#define DIN 1024
#define DOUT 1024
#define NADP 8
#define RANK 16
#define NGRP 64        // E*A groups (convert kernel)
#define MAXTILES 135   // base gemm: 128 full + up to 7 remainders (128-row tiles)
#define MAXP1 520      // pass1: 512 full + up to 8 remainders (32-row tiles)
#define BK 64          // base gemm K-tile

typedef float f32x4 __attribute__((ext_vector_type(4)));
typedef float f32x16 __attribute__((ext_vector_type(16)));
typedef __bf16 bf16x8 __attribute__((ext_vector_type(8)));

typedef __attribute__((address_space(3))) void lds_void;
typedef __attribute__((address_space(1))) void g_void;

static __device__ __forceinline__ unsigned short f2bf(float f) {
    union { float f; unsigned u; } c; c.f = f;
    unsigned r = c.u + 0x7FFFu + ((c.u >> 16) & 1u);
    return (unsigned short)(r >> 16);
}

// ================= fused converts =================
// [0,XB2): x->bf16 grid-stride ; [XB2,XB2+NBW): W->Wt ; +NGRP: lora_A->Agt ; +64: lB->Blt
#define XB2 2048
#define NBW 2048
__global__ __launch_bounds__(256) void k_convert_all(const float* __restrict__ x,
                                                     const float* __restrict__ W,
                                                     const float* __restrict__ lA,
                                                     const float* __restrict__ lB,
                                                     unsigned short* __restrict__ xb,
                                                     unsigned short* __restrict__ Wt,
                                                     unsigned short* __restrict__ Agt,
                                                     unsigned short* __restrict__ Blt) {
    __shared__ __attribute__((aligned(16))) unsigned short lds_u[16 * 1032]; // 33 KB union
    int b = blockIdx.x;
    int t = threadIdx.x;
    if (b < XB2) {
        // ---- convert x (grid-stride), zero-pad 128 extra rows ----
        const size_t total = (size_t)(T_TOK + 128) * DIN / 4;  // float4 units
        const size_t conv  = (size_t)T_TOK * DIN / 4;          // = 8 * XB2 * 256 exactly
        size_t gid = (size_t)b * 256 + t;
#pragma unroll
        for (int it = 0; it < 9; it++) {
            size_t u = gid + (size_t)it * (XB2 * 256);
            if (u < total) {
                ushort4 o;
                if (u < conv) {
                    float4 v = *(const float4*)(x + u * 4);
                    o.x = f2bf(v.x); o.y = f2bf(v.y); o.z = f2bf(v.z); o.w = f2bf(v.w);
                } else {
                    o.x = 0; o.y = 0; o.z = 0; o.w = 0;
                }
                *(ushort4*)(xb + u * 4) = o;
            }
        }
    } else if (b < XB2 + NBW) {
        // ---- convert+transpose W [E][IN][OUT] -> [E][OUT][IN], u32-packed LDS ----
        int idx = b - XB2;
        int e = idx >> 8;
        int k0 = ((idx >> 4) & 15) * 64, n0 = (idx & 15) * 64;
        const float* We = W + (size_t)e * DIN * DOUT;
        unsigned short* Wte = Wt + (size_t)e * DIN * DOUT;
        unsigned* lds32 = (unsigned*)lds_u;            // pitch 34 u32 per n-row
        int kp = t >> 3;                               // k-pair 0..31
        int nc = (t & 7) * 8;                          // 8 cols
        const float* r0 = We + (size_t)(k0 + 2 * kp) * DOUT + n0 + nc;
        const float* r1 = r0 + DOUT;
        float4 a0 = *(const float4*)r0, a1 = *(const float4*)(r0 + 4);
        float4 c0 = *(const float4*)r1, c1 = *(const float4*)(r1 + 4);
        lds32[(nc + 0) * 34 + kp] = (unsigned)f2bf(a0.x) | ((unsigned)f2bf(c0.x) << 16);
        lds32[(nc + 1) * 34 + kp] = (unsigned)f2bf(a0.y) | ((unsigned)f2bf(c0.y) << 16);
        lds32[(nc + 2) * 34 + kp] = (unsigned)f2bf(a0.z) | ((unsigned)f2bf(c0.z) << 16);
        lds32[(nc + 3) * 34 + kp] = (unsigned)f2bf(a0.w) | ((unsigned)f2bf(c0.w) << 16);
        lds32[(nc + 4) * 34 + kp] = (unsigned)f2bf(a1.x) | ((unsigned)f2bf(c1.x) << 16);
        lds32[(nc + 5) * 34 + kp] = (unsigned)f2bf(a1.y) | ((unsigned)f2bf(c1.y) << 16);
        lds32[(nc + 6) * 34 + kp] = (unsigned)f2bf(a1.z) | ((unsigned)f2bf(c1.z) << 16);
        lds32[(nc + 7) * 34 + kp] = (unsigned)f2bf(a1.w) | ((unsigned)f2bf(c1.w) << 16);
        __syncthreads();
        int n = t >> 2, kq = (t & 3) * 8;              // 8 u32 = 16 k per thread
        uint2 d0 = *(const uint2*)&lds32[n * 34 + kq + 0];
        uint2 d1 = *(const uint2*)&lds32[n * 34 + kq + 2];
        uint2 d2 = *(const uint2*)&lds32[n * 34 + kq + 4];
        uint2 d3 = *(const uint2*)&lds32[n * 34 + kq + 6];
        uint4 v0; v0.x = d0.x; v0.y = d0.y; v0.z = d1.x; v0.w = d1.y;
        uint4 v1; v1.x = d2.x; v1.y = d2.y; v1.z = d3.x; v1.w = d3.y;
        *(uint4*)(Wte + (size_t)(n0 + n) * DIN + k0 + kq * 2) = v0;
        *(uint4*)(Wte + (size_t)(n0 + n) * DIN + k0 + kq * 2 + 8) = v1;
    } else if (b < XB2 + NBW + NGRP) {
        // ---- convert+transpose lora_A [A][E][K][R] -> Agt [g=e*8+a][R][K] ----
        int g = b - (XB2 + NBW);
        int a = g & 7, e = g >> 3;
        const float* src = lA + (size_t)(a * NEXP + e) * DIN * RANK;
#pragma unroll
        for (int it = 0; it < 4; it++) {
            int k = it * 256 + t;
            const float4* p = (const float4*)(src + (size_t)k * RANK);
            float4 v0 = p[0], v1 = p[1], v2 = p[2], v3 = p[3];
            lds_u[0 * 1032 + k] = f2bf(v0.x);  lds_u[1 * 1032 + k] = f2bf(v0.y);
            lds_u[2 * 1032 + k] = f2bf(v0.z);  lds_u[3 * 1032 + k] = f2bf(v0.w);
            lds_u[4 * 1032 + k] = f2bf(v1.x);  lds_u[5 * 1032 + k] = f2bf(v1.y);
            lds_u[6 * 1032 + k] = f2bf(v1.z);  lds_u[7 * 1032 + k] = f2bf(v1.w);
            lds_u[8 * 1032 + k] = f2bf(v2.x);  lds_u[9 * 1032 + k] = f2bf(v2.y);
            lds_u[10 * 1032 + k] = f2bf(v2.z); lds_u[11 * 1032 + k] = f2bf(v2.w);
            lds_u[12 * 1032 + k] = f2bf(v3.x); lds_u[13 * 1032 + k] = f2bf(v3.y);
            lds_u[14 * 1032 + k] = f2bf(v3.z); lds_u[15 * 1032 + k] = f2bf(v3.w);
        }
        __syncthreads();
        unsigned short* dst = Agt + (size_t)g * RANK * DIN;
        int r = t >> 4, ks = (t & 15) * 64;
#pragma unroll
        for (int j = 0; j < 8; j++)
            *(uint4*)(dst + r * DIN + ks + j * 8) = *(const uint4*)&lds_u[r * 1032 + ks + j * 8];
    } else {
        // ---- lB [A][E][R][N] fp32 -> Blt [E][N][A*16+R] bf16 (B^T operand for lora MFMA) ----
        int idx = b - (XB2 + NBW + NGRP);
        int e = idx >> 3, nc = idx & 7;           // n chunk of 128
        int k = t >> 1, half = t & 1;
        int a = k >> 4, r = k & 15;
        const float* src = lB + ((size_t)(a * NEXP + e) * RANK + r) * DOUT + nc * 128 + half * 64;
#pragma unroll
        for (int j = 0; j < 16; j++) {
            float4 v = *(const float4*)(src + j * 4);
            int nl = half * 64 + j * 4;
            lds_u[k * 129 + nl + 0] = f2bf(v.x);
            lds_u[k * 129 + nl + 1] = f2bf(v.y);
            lds_u[k * 129 + nl + 2] = f2bf(v.z);
            lds_u[k * 129 + nl + 3] = f2bf(v.w);
        }
        __syncthreads();
        int nl = t >> 1, kh = t & 1;
        unsigned short* dst = Blt + ((size_t)(e * 1024 + nc * 128 + nl)) * 128 + kh * 64;
#pragma unroll
        for (int g2 = 0; g2 < 8; g2++) {
            uint4 pv;
            unsigned short s0 = lds_u[(kh * 64 + g2 * 8 + 0) * 129 + nl];
            unsigned short s1 = lds_u[(kh * 64 + g2 * 8 + 1) * 129 + nl];
            unsigned short s2 = lds_u[(kh * 64 + g2 * 8 + 2) * 129 + nl];
            unsigned short s3 = lds_u[(kh * 64 + g2 * 8 + 3) * 129 + nl];
            unsigned short s4 = lds_u[(kh * 64 + g2 * 8 + 4) * 129 + nl];
            unsigned short s5 = lds_u[(kh * 64 + g2 * 8 + 5) * 129 + nl];
            unsigned short s6 = lds_u[(kh * 64 + g2 * 8 + 6) * 129 + nl];
            unsigned short s7 = lds_u[(kh * 64 + g2 * 8 + 7) * 129 + nl];
            pv.x = (unsigned)s0 | ((unsigned)s1 << 16);
            pv.y = (unsigned)s2 | ((unsigned)s3 << 16);
            pv.z = (unsigned)s4 | ((unsigned)s5 << 16);
            pv.w = (unsigned)s6 | ((unsigned)s7 << 16);
            *(uint4*)(dst + g2 * 8) = pv;
        }
    }
}

// ================= pass1: inter[tok] = s_a * (x[tok] @ lora_A[e, a(tok)]) as bf16 =========
// 32-token tiles (~520 blocks, 2/CU) for latency hiding; no LDS, no barriers.
// Wave owns 2 adapters x 2 rowgroups; computes all 8 adapters per token, masked store.
__global__ __launch_bounds__(256) void k_pass1(const unsigned short* __restrict__ xb,
                                               const unsigned short* __restrict__ Agt,
                                               const int* __restrict__ gs,
                                               const int* __restrict__ aidx,
                                               const float* __restrict__ scal,
                                               unsigned short* __restrict__ interb) {
    int bid = blockIdx.x;
    int e = -1, m0 = 0, valid = 0;
    {
        int acc_t = 0, base = 0;
#pragma unroll
        for (int ee = 0; ee < NEXP; ee++) {
            int sz = gs[ee];
            int nt = (sz + 31) >> 5;
            if (e < 0 && bid < acc_t + nt) {
                int loc = bid - acc_t;
                e = ee; m0 = base + (loc << 5);
                int v = sz - (loc << 5); valid = v > 32 ? 32 : v;
            }
            acc_t += nt; base += sz;
        }
    }
    if (e < 0) return;

    int t = threadIdx.x;
    int lane = t & 63, w = t >> 6;   // wave owns adapters 2w, 2w+1
    int ln = lane & 15, q = lane >> 4;

    const unsigned short* A0 = Agt + ((size_t)(e * NADP + 2 * w) * RANK + ln) * DIN + q * 8;
    const unsigned short* A1 = A0 + (size_t)RANK * DIN;
    const unsigned short* X0 = xb + (size_t)(m0 + ln) * DIN + q * 8;

    f32x4 acc[2][2];
#pragma unroll
    for (int i = 0; i < 2; i++) {
        acc[i][0] = (f32x4){0.f, 0.f, 0.f, 0.f};
        acc[i][1] = (f32x4){0.f, 0.f, 0.f, 0.f};
    }

    // swapped operands: D[row = rank r][col = token], lane holds one token column.
#pragma unroll 4
    for (int k0 = 0; k0 < DIN; k0 += 32) {
        bf16x8 b0 = *(const bf16x8*)(A0 + k0);
        bf16x8 b1 = *(const bf16x8*)(A1 + k0);
#pragma unroll
        for (int rg = 0; rg < 2; rg++) {
            bf16x8 af = *(const bf16x8*)(X0 + (size_t)(rg * 16) * DIN + k0);
            acc[rg][0] = __builtin_amdgcn_mfma_f32_16x16x32_bf16(b0, af, acc[rg][0], 0, 0, 0);
            acc[rg][1] = __builtin_amdgcn_mfma_f32_16x16x32_bf16(b1, af, acc[rg][1], 0, 0, 0);
        }
    }

    float s0 = scal[2 * w], s1 = scal[2 * w + 1];
#pragma unroll
    for (int rg = 0; rg < 2; rg++) {
        int tr = rg * 16 + ln;
        if (tr < valid) {
            int tok = m0 + tr;
            int a = aidx[tok];
            if (a == 2 * w) {
                f32x4 v = acc[rg][0];
                ushort4 u;
                u.x = f2bf(s0 * v[0]); u.y = f2bf(s0 * v[1]);
                u.z = f2bf(s0 * v[2]); u.w = f2bf(s0 * v[3]);
                *(ushort4*)(interb + (size_t)tok * RANK + q * 4) = u;
            } else if (a == 2 * w + 1) {
                f32x4 v = acc[rg][1];
                ushort4 u;
                u.x = f2bf(s1 * v[0]); u.y = f2bf(s1 * v[1]);
                u.z = f2bf(s1 * v[2]); u.w = f2bf(s1 * v[3]);
                *(ushort4*)(interb + (size_t)tok * RANK + q * 4) = u;
            }
        }
    }
}

// ================= base grouped GEMM + fused LoRA-B, 32x32x16 MFMA, 128x128xBK ===========
// grid = dim3(8, MAXTILES). Double-buffered LDS, stage(k+1) overlaps compute(k),
// one __syncthreads per K-step. 32x32 fragments: half the MFMA instruction count,
// C-store writes two full 128B lines per instruction.
__global__ __launch_bounds__(256) void k_gemm(const unsigned short* __restrict__ xb,
                                              const unsigned short* __restrict__ wt,
                                              const int* __restrict__ gs,
                                              const unsigned short* __restrict__ interb,
                                              const int* __restrict__ aidx,
                                              const unsigned short* __restrict__ Blt,
                                              float* __restrict__ out) {
    __shared__ __attribute__((aligned(16))) unsigned short smem[32768]; // 64 KB = 2 x (As 16K + Bs 16K)
    int tileid = blockIdx.y;
    int e = -1, m0 = 0, valid = 0;
    {
        int acc_t = 0, base = 0;
#pragma unroll
        for (int ee = 0; ee < NEXP; ee++) {
            int sz = gs[ee];
            int nt = (sz + 127) >> 7;
            if (e < 0 && tileid < acc_t + nt) {
                int loc = tileid - acc_t;
                e = ee; m0 = base + (loc << 7);
                int v = sz - (loc << 7); valid = v > 128 ? 128 : v;
            }
            acc_t += nt; base += sz;
        }
    }
    if (e < 0) return;
    int n0 = blockIdx.x * 128;

    int t = threadIdx.x;
    int lane = t & 63;
    int wave = t >> 6;
    int wm = wave >> 1, wn = wave & 1;
    int r32 = lane & 31, hi = lane >> 5;

    const unsigned short* wte = wt + (size_t)e * DIN * DOUT;

    f32x16 acc[2][2];
#pragma unroll
    for (int i = 0; i < 2; i++)
#pragma unroll
        for (int j = 0; j < 2; j++) acc[i][j] = (f32x16)(0.f);

    // staging: lane loads global chunk g = (lane&7)^(row&7) so physical LDS slot lane&7
    // holds swizzled content; LDS dest = wave-uniform base + lane*16 (HW constraint).
    int srow[4], skoff[4];
#pragma unroll
    for (int j = 0; j < 4; j++) {
        srow[j]  = j * 32 + wave * 8 + (lane >> 3);
        skoff[j] = ((lane & 7) ^ (srow[j] & 7)) * 8;
    }

    auto STAGE = [&](int buf, int k0) {
#pragma unroll
        for (int j = 0; j < 4; j++) {
            __builtin_amdgcn_global_load_lds(
                (const g_void*)(xb + (size_t)(m0 + srow[j]) * DIN + k0 + skoff[j]),
                (lds_void*)((char*)smem + buf * 32768 + j * 4096 + wave * 1024), 16, 0, 0);
            __builtin_amdgcn_global_load_lds(
                (const g_void*)(wte + (size_t)(n0 + srow[j]) * DIN + k0 + skoff[j]),
                (lds_void*)((char*)smem + buf * 32768 + 16384 + j * 4096 + wave * 1024), 16, 0, 0);
        }
    };

    auto COMPUTE = [&](int buf) {
        const char* Ab = (const char*)smem + buf * 32768;
        const char* Bb = Ab + 16384;
#pragma unroll
        for (int kf = 0; kf < 4; kf++) {
            int kc = kf * 2 + hi;                        // k-chunk 0..7
            int slot = kc ^ (r32 & 7);
            bf16x8 af[2], bfr[2];
#pragma unroll
            for (int mi = 0; mi < 2; mi++) {
                int row = wm * 64 + mi * 32 + r32;
                af[mi] = *(const bf16x8*)(Ab + row * 128 + slot * 16);
            }
#pragma unroll
            for (int ni = 0; ni < 2; ni++) {
                int row = wn * 64 + ni * 32 + r32;
                bfr[ni] = *(const bf16x8*)(Bb + row * 128 + slot * 16);
            }
#pragma unroll
            for (int mi = 0; mi < 2; mi++)
#pragma unroll
                for (int ni = 0; ni < 2; ni++)
                    acc[mi][ni] = __builtin_amdgcn_mfma_f32_32x32x16_bf16(af[mi], bfr[ni], acc[mi][ni], 0, 0, 0);
        }
    };

    // prologue: fill buffer 0
    STAGE(0, 0);
    __syncthreads();
    int cur = 0;
    for (int k0 = BK; k0 < DIN; k0 += BK) {
        STAGE(cur ^ 1, k0);   // prefetch next tile — latency hides under COMPUTE
        COMPUTE(cur);
        __syncthreads();      // drains vmcnt (prefetch done by now) + lgkm, flips buffer
        cur ^= 1;
    }
    COMPUTE(cur);

    // ---- fused LoRA: acc += P @ Blt[e][n0 slab], P[row][a*16+r] = interb[row][r] at slot a ----
    __syncthreads();
    {
        // fold zeroing into the scatter: 2 threads/row each cover 8 of 16 logical slots
        int row = t >> 1, h = t & 1;
        int rs = row & 15;
        uint4 z = {0u, 0u, 0u, 0u};
        uint4 payload = z;
        int pslot = -1;
        if (row < valid) {
            int tok = m0 + row;
            int a = aidx[tok];
            payload = *(const uint4*)(interb + (size_t)tok * RANK + h * 8); // pre-scaled bf16
            pslot = a * 2 + h;
        }
#pragma unroll
        for (int l2 = 0; l2 < 8; l2++) {
            int l = l2 * 2 + h;                       // logical slot, parity h
            int phys = l ^ rs;                        // 16-slot xor swizzle
            *(uint4*)((char*)smem + row * 256 + phys * 16) = (l == pslot) ? payload : z;
        }
    }
    __syncthreads();
#pragma unroll
    for (int kf = 0; kf < 8; kf++) {
        int kc = kf * 2 + hi;                          // k-chunk 0..15
        bf16x8 af[2], bfr[2];
#pragma unroll
        for (int ni = 0; ni < 2; ni++) {
            int n = wn * 64 + ni * 32 + r32;
            bfr[ni] = *(const bf16x8*)(Blt + ((size_t)(e * 1024 + n0 + n)) * 128 + kc * 8);
        }
#pragma unroll
        for (int mi = 0; mi < 2; mi++) {
            int row = wm * 64 + mi * 32 + r32;
            int slot = kc ^ (r32 & 15);                // row&15 == r32&15
            af[mi] = *(const bf16x8*)((const char*)smem + row * 256 + slot * 16);
        }
#pragma unroll
        for (int mi = 0; mi < 2; mi++)
#pragma unroll
            for (int ni = 0; ni < 2; ni++)
                acc[mi][ni] = __builtin_amdgcn_mfma_f32_32x32x16_bf16(af[mi], bfr[ni], acc[mi][ni], 0, 0, 0);
    }

    // ---- store: 32x32 C-map row=(reg&3)+8*(reg>>2)+4*hi, col=r32 → full-line writes ----
#pragma unroll
    for (int mi = 0; mi < 2; mi++) {
#pragma unroll
        for (int r = 0; r < 16; r++) {
            int row32 = (r & 3) + 8 * (r >> 2) + 4 * hi;
            int row_l = wm * 64 + mi * 32 + row32;
            if (row_l < valid) {
                float* orow = out + (size_t)(m0 + row_l) * DOUT + n0 + wn * 64 + r32;
#pragma unroll
                for (int ni = 0; ni < 2; ni++)
                    orow[ni * 32] = acc[mi][ni][r];
            }
        }
    }
}

extern "C" void kernel_launch(void* const* d_in, const int* in_sizes, int n_in,
                              void* d_out, int out_size, void* d_ws, size_t ws_size,
                              hipStream_t stream) {
    (void)in_sizes; (void)n_in; (void)out_size; (void)ws_size;
    const float* x    = (const float*)d_in[0];
    const int*   gs   = (const int*)d_in[1];
    const int*   aidx = (const int*)d_in[2];
    const float* W    = (const float*)d_in[3];
    const float* lA   = (const float*)d_in[4];
    const float* lB   = (const float*)d_in[5];
    const float* scal = (const float*)d_in[6];
    float* out = (float*)d_out;

    // ws layout (16B-aligned)
    char* ws = (char*)d_ws;
    unsigned short* xb     = (unsigned short*)ws;        size_t o = 33816576; // (T+128)*1024*2
    unsigned short* wt     = (unsigned short*)(ws + o);  o += 16777216;       // E*IN*OUT*2
    unsigned short* Agt    = (unsigned short*)(ws + o);  o += 2097152;        // 64*16*1024*2
    unsigned short* Blt    = (unsigned short*)(ws + o);  o += 2097152;        // 8*1024*128*2
    unsigned short* interb = (unsigned short*)(ws + o);  o += 524288;         // T*16*2 (bf16, pre-scaled)

    k_convert_all<<<XB2 + NBW + NGRP + 64, 256, 0, stream>>>(x, W, lA, lB, xb, wt, Agt, Blt);
    k_pass1<<<MAXP1, 256, 0, stream>>>(xb, Agt, gs, aidx, scal, interb);
    k_gemm<<<dim3(8, MAXTILES), 256, 0, stream>>>(xb, wt, gs, interb, aidx, Blt, out);
}

// Round 3
// 264.884 us; speedup vs baseline: 1.1115x; 1.0432x over previous
//
#include <hip/hip_runtime.h>

// Problem constants (LoRAExpert)
#define T_TOK 16384
#define NEXP 8
#define DIN 1024
#define DOUT 1024
#define NADP 8
#define RANK 16
#define NGRP 64        // E*A groups (convert kernel)
#define MAXP1 520      // pass1: 512 full + up to 8 remainders (32-row tiles)
#define BK 64          // base gemm K-tile
#define NKSTEP 16      // DIN / BK

typedef float f32x4 __attribute__((ext_vector_type(4)));
typedef float f32x16 __attribute__((ext_vector_type(16)));
typedef __bf16 bf16x8 __attribute__((ext_vector_type(8)));

typedef __attribute__((address_space(3))) void lds_void;
typedef __attribute__((address_space(1))) void g_void;

static __device__ __forceinline__ unsigned short f2bf(float f) {
    union { float f; unsigned u; } c; c.f = f;
    unsigned r = c.u + 0x7FFFu + ((c.u >> 16) & 1u);
    return (unsigned short)(r >> 16);
}

// ================= fused converts =================
// [0,XB2): x->bf16 grid-stride ; [XB2,XB2+NBW): W->Wt ; +NGRP: lora_A->Agt ; +64: lB->Blt
#define XB2 2048
#define NBW 2048
__global__ __launch_bounds__(256) void k_convert_all(const float* __restrict__ x,
                                                     const float* __restrict__ W,
                                                     const float* __restrict__ lA,
                                                     const float* __restrict__ lB,
                                                     unsigned short* __restrict__ xb,
                                                     unsigned short* __restrict__ Wt,
                                                     unsigned short* __restrict__ Agt,
                                                     unsigned short* __restrict__ Blt) {
    __shared__ __attribute__((aligned(16))) unsigned short lds_u[16 * 1032]; // 33 KB union
    int b = blockIdx.x;
    int t = threadIdx.x;
    if (b < XB2) {
        // ---- convert x (grid-stride), zero-pad 128 extra rows ----
        const size_t total = (size_t)(T_TOK + 128) * DIN / 4;  // float4 units
        const size_t conv  = (size_t)T_TOK * DIN / 4;          // = 8 * XB2 * 256 exactly
        size_t gid = (size_t)b * 256 + t;
#pragma unroll
        for (int it = 0; it < 9; it++) {
            size_t u = gid + (size_t)it * (XB2 * 256);
            if (u < total) {
                ushort4 o;
                if (u < conv) {
                    float4 v = *(const float4*)(x + u * 4);
                    o.x = f2bf(v.x); o.y = f2bf(v.y); o.z = f2bf(v.z); o.w = f2bf(v.w);
                } else {
                    o.x = 0; o.y = 0; o.z = 0; o.w = 0;
                }
                *(ushort4*)(xb + u * 4) = o;
            }
        }
    } else if (b < XB2 + NBW) {
        // ---- convert+transpose W [E][IN][OUT] -> [E][OUT][IN], u32-packed LDS ----
        int idx = b - XB2;
        int e = idx >> 8;
        int k0 = ((idx >> 4) & 15) * 64, n0 = (idx & 15) * 64;
        const float* We = W + (size_t)e * DIN * DOUT;
        unsigned short* Wte = Wt + (size_t)e * DIN * DOUT;
        unsigned* lds32 = (unsigned*)lds_u;            // pitch 34 u32 per n-row
        int kp = t >> 3;                               // k-pair 0..31
        int nc = (t & 7) * 8;                          // 8 cols
        const float* r0 = We + (size_t)(k0 + 2 * kp) * DOUT + n0 + nc;
        const float* r1 = r0 + DOUT;
        float4 a0 = *(const float4*)r0, a1 = *(const float4*)(r0 + 4);
        float4 c0 = *(const float4*)r1, c1 = *(const float4*)(r1 + 4);
        lds32[(nc + 0) * 34 + kp] = (unsigned)f2bf(a0.x) | ((unsigned)f2bf(c0.x) << 16);
        lds32[(nc + 1) * 34 + kp] = (unsigned)f2bf(a0.y) | ((unsigned)f2bf(c0.y) << 16);
        lds32[(nc + 2) * 34 + kp] = (unsigned)f2bf(a0.z) | ((unsigned)f2bf(c0.z) << 16);
        lds32[(nc + 3) * 34 + kp] = (unsigned)f2bf(a0.w) | ((unsigned)f2bf(c0.w) << 16);
        lds32[(nc + 4) * 34 + kp] = (unsigned)f2bf(a1.x) | ((unsigned)f2bf(c1.x) << 16);
        lds32[(nc + 5) * 34 + kp] = (unsigned)f2bf(a1.y) | ((unsigned)f2bf(c1.y) << 16);
        lds32[(nc + 6) * 34 + kp] = (unsigned)f2bf(a1.z) | ((unsigned)f2bf(c1.z) << 16);
        lds32[(nc + 7) * 34 + kp] = (unsigned)f2bf(a1.w) | ((unsigned)f2bf(c1.w) << 16);
        __syncthreads();
        int n = t >> 2, kq = (t & 3) * 8;              // 8 u32 = 16 k per thread
        uint2 d0 = *(const uint2*)&lds32[n * 34 + kq + 0];
        uint2 d1 = *(const uint2*)&lds32[n * 34 + kq + 2];
        uint2 d2 = *(const uint2*)&lds32[n * 34 + kq + 4];
        uint2 d3 = *(const uint2*)&lds32[n * 34 + kq + 6];
        uint4 v0; v0.x = d0.x; v0.y = d0.y; v0.z = d1.x; v0.w = d1.y;
        uint4 v1; v1.x = d2.x; v1.y = d2.y; v1.z = d3.x; v1.w = d3.y;
        *(uint4*)(Wte + (size_t)(n0 + n) * DIN + k0 + kq * 2) = v0;
        *(uint4*)(Wte + (size_t)(n0 + n) * DIN + k0 + kq * 2 + 8) = v1;
    } else if (b < XB2 + NBW + NGRP) {
        // ---- convert+transpose lora_A [A][E][K][R] -> Agt [g=e*8+a][R][K] ----
        int g = b - (XB2 + NBW);
        int a = g & 7, e = g >> 3;
        const float* src = lA + (size_t)(a * NEXP + e) * DIN * RANK;
#pragma unroll
        for (int it = 0; it < 4; it++) {
            int k = it * 256 + t;
            const float4* p = (const float4*)(src + (size_t)k * RANK);
            float4 v0 = p[0], v1 = p[1], v2 = p[2], v3 = p[3];
            lds_u[0 * 1032 + k] = f2bf(v0.x);  lds_u[1 * 1032 + k] = f2bf(v0.y);
            lds_u[2 * 1032 + k] = f2bf(v0.z);  lds_u[3 * 1032 + k] = f2bf(v0.w);
            lds_u[4 * 1032 + k] = f2bf(v1.x);  lds_u[5 * 1032 + k] = f2bf(v1.y);
            lds_u[6 * 1032 + k] = f2bf(v1.z);  lds_u[7 * 1032 + k] = f2bf(v1.w);
            lds_u[8 * 1032 + k] = f2bf(v2.x);  lds_u[9 * 1032 + k] = f2bf(v2.y);
            lds_u[10 * 1032 + k] = f2bf(v2.z); lds_u[11 * 1032 + k] = f2bf(v2.w);
            lds_u[12 * 1032 + k] = f2bf(v3.x); lds_u[13 * 1032 + k] = f2bf(v3.y);
            lds_u[14 * 1032 + k] = f2bf(v3.z); lds_u[15 * 1032 + k] = f2bf(v3.w);
        }
        __syncthreads();
        unsigned short* dst = Agt + (size_t)g * RANK * DIN;
        int r = t >> 4, ks = (t & 15) * 64;
#pragma unroll
        for (int j = 0; j < 8; j++)
            *(uint4*)(dst + r * DIN + ks + j * 8) = *(const uint4*)&lds_u[r * 1032 + ks + j * 8];
    } else {
        // ---- lB [A][E][R][N] fp32 -> Blt [E][N][A*16+R] bf16 (B^T operand for lora MFMA) ----
        int idx = b - (XB2 + NBW + NGRP);
        int e = idx >> 3, nc = idx & 7;           // n chunk of 128
        int k = t >> 1, half = t & 1;
        int a = k >> 4, r = k & 15;
        const float* src = lB + ((size_t)(a * NEXP + e) * RANK + r) * DOUT + nc * 128 + half * 64;
#pragma unroll
        for (int j = 0; j < 16; j++) {
            float4 v = *(const float4*)(src + j * 4);
            int nl = half * 64 + j * 4;
            lds_u[k * 129 + nl + 0] = f2bf(v.x);
            lds_u[k * 129 + nl + 1] = f2bf(v.y);
            lds_u[k * 129 + nl + 2] = f2bf(v.z);
            lds_u[k * 129 + nl + 3] = f2bf(v.w);
        }
        __syncthreads();
        int nl = t >> 1, kh = t & 1;
        unsigned short* dst = Blt + ((size_t)(e * 1024 + nc * 128 + nl)) * 128 + kh * 64;
#pragma unroll
        for (int g2 = 0; g2 < 8; g2++) {
            uint4 pv;
            unsigned short s0 = lds_u[(kh * 64 + g2 * 8 + 0) * 129 + nl];
            unsigned short s1 = lds_u[(kh * 64 + g2 * 8 + 1) * 129 + nl];
            unsigned short s2 = lds_u[(kh * 64 + g2 * 8 + 2) * 129 + nl];
            unsigned short s3 = lds_u[(kh * 64 + g2 * 8 + 3) * 129 + nl];
            unsigned short s4 = lds_u[(kh * 64 + g2 * 8 + 4) * 129 + nl];
            unsigned short s5 = lds_u[(kh * 64 + g2 * 8 + 5) * 129 + nl];
            unsigned short s6 = lds_u[(kh * 64 + g2 * 8 + 6) * 129 + nl];
            unsigned short s7 = lds_u[(kh * 64 + g2 * 8 + 7) * 129 + nl];
            pv.x = (unsigned)s0 | ((unsigned)s1 << 16);
            pv.y = (unsigned)s2 | ((unsigned)s3 << 16);
            pv.z = (unsigned)s4 | ((unsigned)s5 << 16);
            pv.w = (unsigned)s6 | ((unsigned)s7 << 16);
            *(uint4*)(dst + g2 * 8) = pv;
        }
    }
}

// ================= pass1: inter[tok] = s_a * (x[tok] @ lora_A[e, a(tok)]) as bf16 =========
__global__ __launch_bounds__(256) void k_pass1(const unsigned short* __restrict__ xb,
                                               const unsigned short* __restrict__ Agt,
                                               const int* __restrict__ gs,
                                               const int* __restrict__ aidx,
                                               const float* __restrict__ scal,
                                               unsigned short* __restrict__ interb) {
    int bid = blockIdx.x;
    int e = -1, m0 = 0, valid = 0;
    {
        int acc_t = 0, base = 0;
#pragma unroll
        for (int ee = 0; ee < NEXP; ee++) {
            int sz = gs[ee];
            int nt = (sz + 31) >> 5;
            if (e < 0 && bid < acc_t + nt) {
                int loc = bid - acc_t;
                e = ee; m0 = base + (loc << 5);
                int v = sz - (loc << 5); valid = v > 32 ? 32 : v;
            }
            acc_t += nt; base += sz;
        }
    }
    if (e < 0) return;

    int t = threadIdx.x;
    int lane = t & 63, w = t >> 6;   // wave owns adapters 2w, 2w+1
    int ln = lane & 15, q = lane >> 4;

    const unsigned short* A0 = Agt + ((size_t)(e * NADP + 2 * w) * RANK + ln) * DIN + q * 8;
    const unsigned short* A1 = A0 + (size_t)RANK * DIN;
    const unsigned short* X0 = xb + (size_t)(m0 + ln) * DIN + q * 8;

    f32x4 acc[2][2];
#pragma unroll
    for (int i = 0; i < 2; i++) {
        acc[i][0] = (f32x4){0.f, 0.f, 0.f, 0.f};
        acc[i][1] = (f32x4){0.f, 0.f, 0.f, 0.f};
    }

    // swapped operands: D[row = rank r][col = token], lane holds one token column.
#pragma unroll 4
    for (int k0 = 0; k0 < DIN; k0 += 32) {
        bf16x8 b0 = *(const bf16x8*)(A0 + k0);
        bf16x8 b1 = *(const bf16x8*)(A1 + k0);
#pragma unroll
        for (int rg = 0; rg < 2; rg++) {
            bf16x8 af = *(const bf16x8*)(X0 + (size_t)(rg * 16) * DIN + k0);
            acc[rg][0] = __builtin_amdgcn_mfma_f32_16x16x32_bf16(b0, af, acc[rg][0], 0, 0, 0);
            acc[rg][1] = __builtin_amdgcn_mfma_f32_16x16x32_bf16(b1, af, acc[rg][1], 0, 0, 0);
        }
    }

    float s0 = scal[2 * w], s1 = scal[2 * w + 1];
#pragma unroll
    for (int rg = 0; rg < 2; rg++) {
        int tr = rg * 16 + ln;
        if (tr < valid) {
            int tok = m0 + tr;
            int a = aidx[tok];
            if (a == 2 * w) {
                f32x4 v = acc[rg][0];
                ushort4 u;
                u.x = f2bf(s0 * v[0]); u.y = f2bf(s0 * v[1]);
                u.z = f2bf(s0 * v[2]); u.w = f2bf(s0 * v[3]);
                *(ushort4*)(interb + (size_t)tok * RANK + q * 4) = u;
            } else if (a == 2 * w + 1) {
                f32x4 v = acc[rg][1];
                ushort4 u;
                u.x = f2bf(s1 * v[0]); u.y = f2bf(s1 * v[1]);
                u.z = f2bf(s1 * v[2]); u.w = f2bf(s1 * v[3]);
                *(ushort4*)(interb + (size_t)tok * RANK + q * 4) = u;
            }
        }
    }
}

// ================= base grouped GEMM + fused LoRA-B, 32x32x16 MFMA, 128x128xBK ===========
// grid = dim3(8, 136), XCD-affine remap: all 8 n-blocks of a tile AND all tiles of an
// expert land on one XCD (L2 reuse of xb tiles + Wt panels).
// Counted-vmcnt double-buffer pipeline: prologue stages 2 K-tiles; loop waits vmcnt(8)
// (one tile stays in flight across the barrier — never drains to 0), raw s_barrier x2.
__global__ __launch_bounds__(256) void k_gemm(const unsigned short* __restrict__ xb,
                                              const unsigned short* __restrict__ wt,
                                              const int* __restrict__ gs,
                                              const unsigned short* __restrict__ interb,
                                              const int* __restrict__ aidx,
                                              const unsigned short* __restrict__ Blt,
                                              float* __restrict__ out) {
    __shared__ __attribute__((aligned(16))) unsigned short smem[32768]; // 64 KB = 2 x (As 16K + Bs 16K)

    // ---- XCD-affine remap (bijective on 8x136 grid) ----
    int id = blockIdx.y * 8 + blockIdx.x;     // 0..1087; HW: id%8 = XCD
    int xcd = id & 7;
    int j = id >> 3;                          // 0..135
    int tileid = xcd * 17 + (j >> 3);         // 0..135 ; same tile -> ids 8 apart -> same XCD
    int n0 = (j & 7) * 128;

    int e = -1, m0 = 0, valid = 0;
    {
        int acc_t = 0, base = 0;
#pragma unroll
        for (int ee = 0; ee < NEXP; ee++) {
            int sz = gs[ee];
            int nt = (sz + 127) >> 7;
            if (e < 0 && tileid < acc_t + nt) {
                int loc = tileid - acc_t;
                e = ee; m0 = base + (loc << 7);
                int v = sz - (loc << 7); valid = v > 128 ? 128 : v;
            }
            acc_t += nt; base += sz;
        }
    }
    if (e < 0) return;

    int t = threadIdx.x;
    int lane = t & 63;
    int wave = t >> 6;
    int wm = wave >> 1, wn = wave & 1;
    int r32 = lane & 31, hi = lane >> 5;

    const unsigned short* wte = wt + (size_t)e * DIN * DOUT;

    f32x16 acc[2][2];
#pragma unroll
    for (int i = 0; i < 2; i++)
#pragma unroll
        for (int j2 = 0; j2 < 2; j2++) acc[i][j2] = (f32x16)(0.f);

    // staging: lane loads global chunk g = (lane&7)^(row&7) so physical LDS slot lane&7
    // holds swizzled content; LDS dest = wave-uniform base + lane*16 (HW constraint).
    int srow[4], skoff[4];
#pragma unroll
    for (int j3 = 0; j3 < 4; j3++) {
        srow[j3]  = j3 * 32 + wave * 8 + (lane >> 3);
        skoff[j3] = ((lane & 7) ^ (srow[j3] & 7)) * 8;
    }

    auto STAGE = [&](int buf, int k0) {   // 8 global_load_lds per thread
#pragma unroll
        for (int j3 = 0; j3 < 4; j3++) {
            __builtin_amdgcn_global_load_lds(
                (const g_void*)(xb + (size_t)(m0 + srow[j3]) * DIN + k0 + skoff[j3]),
                (lds_void*)((char*)smem + buf * 32768 + j3 * 4096 + wave * 1024), 16, 0, 0);
            __builtin_amdgcn_global_load_lds(
                (const g_void*)(wte + (size_t)(n0 + srow[j3]) * DIN + k0 + skoff[j3]),
                (lds_void*)((char*)smem + buf * 32768 + 16384 + j3 * 4096 + wave * 1024), 16, 0, 0);
        }
    };

    auto COMPUTE = [&](int buf) {
        const char* Ab = (const char*)smem + buf * 32768;
        const char* Bb = Ab + 16384;
        __builtin_amdgcn_s_setprio(1);
#pragma unroll
        for (int kf = 0; kf < 4; kf++) {
            int kc = kf * 2 + hi;                        // k-chunk 0..7
            int slot = kc ^ (r32 & 7);
            bf16x8 af[2], bfr[2];
#pragma unroll
            for (int mi = 0; mi < 2; mi++) {
                int row = wm * 64 + mi * 32 + r32;
                af[mi] = *(const bf16x8*)(Ab + row * 128 + slot * 16);
            }
#pragma unroll
            for (int ni = 0; ni < 2; ni++) {
                int row = wn * 64 + ni * 32 + r32;
                bfr[ni] = *(const bf16x8*)(Bb + row * 128 + slot * 16);
            }
#pragma unroll
            for (int mi = 0; mi < 2; mi++)
#pragma unroll
                for (int ni = 0; ni < 2; ni++)
                    acc[mi][ni] = __builtin_amdgcn_mfma_f32_32x32x16_bf16(af[mi], bfr[ni], acc[mi][ni], 0, 0, 0);
        }
        __builtin_amdgcn_s_setprio(0);
    };

    // ---- pipelined K-loop: 2 tiles in flight, never drain vmcnt to 0 in steady state ----
    STAGE(0, 0);
    STAGE(1, BK);
#pragma unroll
    for (int ts = 0; ts < NKSTEP; ts++) {
        if (ts < NKSTEP - 1) asm volatile("s_waitcnt vmcnt(8)" ::: "memory");  // stage(ts) done
        else                 asm volatile("s_waitcnt vmcnt(0)" ::: "memory");
        __builtin_amdgcn_s_barrier();          // all waves' stage(ts) complete
        COMPUTE(ts & 1);
        if (ts < NKSTEP - 2) {
            __builtin_amdgcn_s_barrier();      // all waves done reading buf before overwrite
            STAGE(ts & 1, (ts + 2) * BK);
        }
    }

    // ---- fused LoRA: acc += P @ Blt[e][n0 slab], P[row][a*16+r] = interb[row][r] at slot a
    // (scatter targets buf0; all waves are past the ts=NKSTEP-1 barrier, so buf0 is free)
    {
        int row = t >> 1, h = t & 1;
        int rs = row & 15;
        uint4 z = {0u, 0u, 0u, 0u};
        uint4 payload = z;
        int pslot = -1;
        if (row < valid) {
            int tok = m0 + row;
            int a = aidx[tok];
            payload = *(const uint4*)(interb + (size_t)tok * RANK + h * 8); // pre-scaled bf16
            pslot = a * 2 + h;
        }
#pragma unroll
        for (int l2 = 0; l2 < 8; l2++) {
            int l = l2 * 2 + h;                       // logical slot, parity h
            int phys = l ^ rs;                        // 16-slot xor swizzle
            *(uint4*)((char*)smem + row * 256 + phys * 16) = (l == pslot) ? payload : z;
        }
    }
    __syncthreads();
#pragma unroll
    for (int kf = 0; kf < 8; kf++) {
        int kc = kf * 2 + hi;                          // k-chunk 0..15
        bf16x8 af[2], bfr[2];
#pragma unroll
        for (int ni = 0; ni < 2; ni++) {
            int n = wn * 64 + ni * 32 + r32;
            bfr[ni] = *(const bf16x8*)(Blt + ((size_t)(e * 1024 + n0 + n)) * 128 + kc * 8);
        }
#pragma unroll
        for (int mi = 0; mi < 2; mi++) {
            int row = wm * 64 + mi * 32 + r32;
            int slot = kc ^ (r32 & 15);                // row&15 == r32&15
            af[mi] = *(const bf16x8*)((const char*)smem + row * 256 + slot * 16);
        }
#pragma unroll
        for (int mi = 0; mi < 2; mi++)
#pragma unroll
            for (int ni = 0; ni < 2; ni++)
                acc[mi][ni] = __builtin_amdgcn_mfma_f32_32x32x16_bf16(af[mi], bfr[ni], acc[mi][ni], 0, 0, 0);
    }

    // ---- store: 32x32 C-map row=(reg&3)+8*(reg>>2)+4*hi, col=r32 → full-line writes ----
#pragma unroll
    for (int mi = 0; mi < 2; mi++) {
#pragma unroll
        for (int r = 0; r < 16; r++) {
            int row32 = (r & 3) + 8 * (r >> 2) + 4 * hi;
            int row_l = wm * 64 + mi * 32 + row32;
            if (row_l < valid) {
                float* orow = out + (size_t)(m0 + row_l) * DOUT + n0 + wn * 64 + r32;
#pragma unroll
                for (int ni = 0; ni < 2; ni++)
                    orow[ni * 32] = acc[mi][ni][r];
            }
        }
    }
}

extern "C" void kernel_launch(void* const* d_in, const int* in_sizes, int n_in,
                              void* d_out, int out_size, void* d_ws, size_t ws_size,
                              hipStream_t stream) {
    (void)in_sizes; (void)n_in; (void)out_size; (void)ws_size;
    const float* x    = (const float*)d_in[0];
    const int*   gs   = (const int*)d_in[1];
    const int*   aidx = (const int*)d_in[2];
    const float* W    = (const float*)d_in[3];
    const float* lA   = (const float*)d_in[4];
    const float* lB   = (const float*)d_in[5];
    const float* scal = (const float*)d_in[6];
    float* out = (float*)d_out;

    // ws layout (16B-aligned)
    char* ws = (char*)d_ws;
    unsigned short* xb     = (unsigned short*)ws;        size_t o = 33816576; // (T+128)*1024*2
    unsigned short* wt     = (unsigned short*)(ws + o);  o += 16777216;       // E*IN*OUT*2
    unsigned short* Agt    = (unsigned short*)(ws + o);  o += 2097152;        // 64*16*1024*2
    unsigned short* Blt    = (unsigned short*)(ws + o);  o += 2097152;        // 8*1024*128*2
    unsigned short* interb = (unsigned short*)(ws + o);  o += 524288;         // T*16*2 (bf16, pre-scaled)

    k_convert_all<<<XB2 + NBW + NGRP + 64, 256, 0, stream>>>(x, W, lA, lB, xb, wt, Agt, Blt);
    k_pass1<<<MAXP1, 256, 0, stream>>>(xb, Agt, gs, aidx, scal, interb);
    k_gemm<<<dim3(8, 136), 256, 0, stream>>>(xb, wt, gs, interb, aidx, Blt, out);
}